// Round 3
// baseline (280.889 us; speedup 1.0000x reference)
//
#include <hip/hip_runtime.h>
#include <hip/hip_bf16.h>
#include <math.h>

#define B_  16
#define C_  64
#define H_  128
#define W_  128
#define HW_ (H_ * W_)
#define K9C (9 * C_)   // 576
#define SEC 16
#define TW  130        // transposed buffer spatial dim (128 + 2 halo)
#define PSTR 40        // LDS pixel stride in ushorts (32 ch + 8 pad)

typedef float f32x4 __attribute__((ext_vector_type(4)));
typedef __bf16 bf16x8 __attribute__((ext_vector_type(8)));

static __device__ __forceinline__ unsigned short f2us(float f) {
    __bf16 h = (__bf16)f;
    return __builtin_bit_cast(unsigned short, h);
}

// ---------------------------------------------------------------------------
// K1: x (NCHW fp32) -> t (b, y', x', c) bf16 with zeroed 1-px halo border.
// Also emits per-(b,row) channel sums -> y0p[b][c][y] (fused global-avg-pool).
// grid = B*H blocks (one row each), 256 threads.
__global__ void k_tr(const float* __restrict__ x, unsigned short* __restrict__ t,
                     float* __restrict__ y0p) {
    int blk = blockIdx.x;
    int b = blk >> 7, y = blk & 127;
    __shared__ unsigned short lds[C_ * TW];   // [c][x], x-stride 130
    int tid = threadIdx.x;
    float ps[8];
    // phase 1: coalesced read of 64 channel-rows, convert to bf16 into LDS
    #pragma unroll
    for (int k = 0; k < 8; ++k) {
        int i = tid + (k << 8);
        int c = i >> 5, xq = i & 31;
        float4 v = *(const float4*)(x + (((size_t)(b * C_ + c)) << 14) + (y << 7) + (xq << 2));
        unsigned int p0 = f2us(v.x) | ((unsigned int)f2us(v.y) << 16);
        unsigned int p1 = f2us(v.z) | ((unsigned int)f2us(v.w) << 16);
        *(unsigned int*)&lds[c * TW + (xq << 2)]     = p0;
        *(unsigned int*)&lds[c * TW + (xq << 2) + 2] = p1;
        ps[k] = v.x + v.y + v.z + v.w;
    }
    // mean partials: reduce over the 32 threads sharing a channel (width-32)
    #pragma unroll
    for (int off = 16; off > 0; off >>= 1) {
        #pragma unroll
        for (int k = 0; k < 8; ++k) ps[k] += __shfl_down(ps[k], off, 32);
    }
    if ((tid & 31) == 0) {
        int a = tid >> 5;
        #pragma unroll
        for (int k = 0; k < 8; ++k)
            y0p[((size_t)(b * C_ + a + (k << 3))) * 128 + y] = ps[k];
    }
    __syncthreads();
    // phase 2: transpose to pixel-major, channel-minor; write row y+1 of t
    size_t rowbase = ((size_t)(b * TW + y + 1)) * TW * C_;
    for (int j = tid; j < 128 * 16; j += 256) {
        int px = j >> 4, g = j & 15;
        unsigned short a0 = lds[(4 * g + 0) * TW + px];
        unsigned short a1 = lds[(4 * g + 1) * TW + px];
        unsigned short a2 = lds[(4 * g + 2) * TW + px];
        unsigned short a3 = lds[(4 * g + 3) * TW + px];
        uint2 wv;
        wv.x = a0 | ((unsigned int)a1 << 16);
        wv.y = a2 | ((unsigned int)a3 << 16);
        *(uint2*)(t + rowbase + (size_t)(px + 1) * C_ + (g << 2)) = wv;
    }
    // halo: zero columns x'=0 and x'=129 of this row
    if (tid < 16) {
        int px = (tid < 8) ? 0 : (TW - 1);
        int ch = tid & 7;
        uint4 z = {0, 0, 0, 0};
        *(uint4*)(t + rowbase + (size_t)px * C_ + ch * 8) = z;
    }
    // halo: zero full rows y'=0 / y'=129
    if (y == 0) {
        size_t base = (size_t)b * TW * TW * C_;
        uint4 z = {0, 0, 0, 0};
        for (int i = tid; i < TW * C_ / 8; i += 256)
            *(uint4*)(t + base + (size_t)i * 8) = z;
    }
    if (y == 127) {
        size_t base = ((size_t)(b * TW + TW - 1)) * TW * C_;
        uint4 z = {0, 0, 0, 0};
        for (int i = tid; i < TW * C_ / 8; i += 256)
            *(uint4*)(t + base + (size_t)i * 8) = z;
    }
}

// ---------------------------------------------------------------------------
// K2: transpose se_w1 [16][64][9] -> w1t [tap][o][c] bf16
__global__ void k_w1t(const float* __restrict__ se_w1, unsigned short* __restrict__ w1t) {
    int idx = blockIdx.x * 256 + threadIdx.x;   // < 9*16*64 = 9216
    int tap = idx >> 10, o = (idx >> 6) & 15, c = idx & 63;
    w1t[idx] = f2us(se_w1[(o * C_ + c) * 9 + tap]);
}

// ---------------------------------------------------------------------------
// K3: reduce y0p -> mean, FC1+relu, FC2+sigmoid -> sgm[b][576]
// grid = B blocks, 256 threads
__global__ void k_fc(const float* __restrict__ y0p,
                     const float* __restrict__ fc_w1,
                     const float* __restrict__ fc_w2,
                     float* __restrict__ sgm) {
    int b = blockIdx.x, t = threadIdx.x;
    __shared__ float red[256];
    __shared__ float sy0[C_];
    __shared__ float sh[4];
    int c = t & 63, part = t >> 6;
    float s = 0.f;
    const float* p = y0p + ((size_t)(b * C_ + c)) * 128 + part * 32;
    for (int yy = 0; yy < 32; ++yy) s += p[yy];
    red[t] = s;
    __syncthreads();
    if (t < C_) {
        float tot = red[t] + red[t + 64] + red[t + 128] + red[t + 192];
        sy0[t] = tot * (1.0f / (float)HW_);
    }
    __syncthreads();
    if (t < 4) {
        float a = 0.f;
        for (int cc = 0; cc < C_; ++cc) a = fmaf(fc_w1[t * C_ + cc], sy0[cc], a);
        sh[t] = fmaxf(a, 0.f);
    }
    __syncthreads();
    for (int i = t; i < K9C; i += 256) {
        float a = 0.f;
        #pragma unroll
        for (int j = 0; j < 4; ++j) a = fmaf(fc_w2[i * 4 + j], sh[j], a);
        sgm[b * K9C + i] = 1.f / (1.f + expf(-a));
    }
}

// ---------------------------------------------------------------------------
// K4: build w_t[b][tap][o][c] = bf16(weight[o][c][tap] * sgm[b][c*9+tap])
// grid = B*9 blocks (b, tap), 256 threads
__global__ void k_wt(const float* __restrict__ weight,
                     const float* __restrict__ sgm,
                     unsigned short* __restrict__ w_t) {
    int blk = blockIdx.x;
    int b = blk / 9, tap = blk - b * 9;
    int t = threadIdx.x;
    __shared__ float lsy[K9C];
    for (int i = t; i < K9C; i += 256) lsy[i] = sgm[b * K9C + i];
    __syncthreads();
    unsigned short* wb = w_t + ((size_t)b * 9 + tap) * 4096;
    #pragma unroll
    for (int k = 0; k < 16; ++k) {
        int i = t + (k << 8);
        int o = i >> 6, c = i & 63;
        wb[i] = f2us(weight[(o * C_ + c) * 9 + tap] * lsy[c * 9 + tap]);
    }
}

// ---------------------------------------------------------------------------
// K5: SE conv1 via MFMA, channel-split staging (32 ch/group) + relu -> mid NHWC
__global__ void __launch_bounds__(256, 4)
k_se1(const unsigned short* __restrict__ t, const unsigned short* __restrict__ w1t,
      unsigned short* __restrict__ mid) {
    int blk = blockIdx.x;
    int b = blk >> 6, tile = blk & 63;
    int ty0 = (tile >> 3) << 4, tx0 = (tile & 7) << 4;
    int tid = threadIdx.x, lane = tid & 63, wave = tid >> 6;
    int n = lane & 15, q = lane >> 4, qc = q << 3;
    __shared__ __align__(16) unsigned short xt[324 * PSTR];
    const unsigned short* tb = t + ((size_t)b * TW + ty0) * TW * C_ + (size_t)tx0 * C_;
    f32x4 acc[4] = {};
    #pragma unroll
    for (int g = 0; g < 2; ++g) {
        if (g) __syncthreads();
        for (int k = 0; k < 6; ++k) {
            int i = tid + (k << 8);
            if (i < 1296) {
                int pl = i >> 2, ch = i & 3;
                int row = pl / 18, col = pl - row * 18;
                uint4 v = *(const uint4*)(tb + ((size_t)row * TW + col) * C_ + (g << 5) + (ch << 3));
                *(uint4*)&xt[pl * PSTR + (ch << 3)] = v;
            }
        }
        __syncthreads();
        uint4 af[9];
        #pragma unroll
        for (int tap = 0; tap < 9; ++tap)
            af[tap] = *(const uint4*)(w1t + ((tap * 16 + n) << 6) + (g << 5) + qc);
        #pragma unroll
        for (int tap = 0; tap < 9; ++tap) {
            int ki = tap / 3, kj = tap - ki * 3;
            int xl = n + kj;
            #pragma unroll
            for (int j = 0; j < 4; ++j) {
                int yl = 4 * wave + j + ki;
                bf16x8 bf = *(const bf16x8*)&xt[(yl * 18 + xl) * PSTR + qc];
                acc[j] = __builtin_amdgcn_mfma_f32_16x16x32_bf16(
                    __builtin_bit_cast(bf16x8, af[tap]), bf, acc[j], 0, 0, 0);
            }
        }
    }
    #pragma unroll
    for (int j = 0; j < 4; ++j) {
        int y = ty0 + 4 * wave + j, xx = tx0 + n;
        uint2 wv;
        float v0 = fmaxf(acc[j][0], 0.f), v1 = fmaxf(acc[j][1], 0.f);
        float v2 = fmaxf(acc[j][2], 0.f), v3 = fmaxf(acc[j][3], 0.f);
        wv.x = f2us(v0) | ((unsigned int)f2us(v1) << 16);
        wv.y = f2us(v2) | ((unsigned int)f2us(v3) << 16);
        *(uint2*)(mid + (((size_t)(b << 14) + (y << 7) + xx) << 4) + (q << 2)) = wv;
    }
}

// ---------------------------------------------------------------------------
// K6: SE conv2 (16->1) + sigmoid -> A[b,HW] fp32
__global__ void k_se2(const unsigned short* __restrict__ mid,
                      const float* __restrict__ se_w2,
                      float* __restrict__ A) {
    int idx = blockIdx.x * 256 + threadIdx.x;
    int b = idx >> 14, l = idx & (HW_ - 1);
    int y = l >> 7, xx = l & 127;
    const unsigned short* mb = mid + (((size_t)b) << 14) * 16;
    float s = 0.f;
    #pragma unroll
    for (int ki = 0; ki < 3; ++ki) {
        int yy = y + ki - 1;
        if (yy < 0 || yy >= H_) continue;
        #pragma unroll
        for (int kj = 0; kj < 3; ++kj) {
            int x2 = xx + kj - 1;
            if (x2 < 0 || x2 >= W_) continue;
            const unsigned short* pp = mb + (((size_t)(yy << 7) + x2) << 4);
            bf16x8 v0 = *(const bf16x8*)pp;
            bf16x8 v1 = *(const bf16x8*)(pp + 8);
            #pragma unroll
            for (int e = 0; e < 8; ++e) {
                s = fmaf((float)v0[e], se_w2[e * 9 + ki * 3 + kj], s);
                s = fmaf((float)v1[e], se_w2[(e + 8) * 9 + ki * 3 + kj], s);
            }
        }
    }
    A[idx] = 1.f / (1.f + expf(-s));
}

// ---------------------------------------------------------------------------
// K7: main conv via MFMA, channel-split staging + A-frag double-buffer prefetch.
// grid = 1024 blocks (exactly 4/CU resident), block 256.
__global__ void __launch_bounds__(256, 4)
k_main(const unsigned short* __restrict__ t, const unsigned short* __restrict__ w_t,
       const float* __restrict__ A, float* __restrict__ out) {
    int blk = blockIdx.x;
    int b = blk >> 6, tile = blk & 63;
    int ty0 = (tile >> 3) << 4, tx0 = (tile & 7) << 4;
    int tid = threadIdx.x, lane = tid & 63, wave = tid >> 6;
    int n = lane & 15, q = lane >> 4, qc = q << 3;
    __shared__ __align__(16) unsigned short xt[324 * PSTR];   // 25.9 KB
    const unsigned short* tb = t + ((size_t)b * TW + ty0) * TW * C_ + (size_t)tx0 * C_;
    const unsigned short* wb = w_t + (size_t)b * 9 * 4096;
    f32x4 acc[4][4] = {};   // [m-tile][row j]
    #pragma unroll
    for (int g = 0; g < 2; ++g) {
        if (g) __syncthreads();
        for (int k = 0; k < 6; ++k) {
            int i = tid + (k << 8);
            if (i < 1296) {
                int pl = i >> 2, ch = i & 3;
                int row = pl / 18, col = pl - row * 18;
                uint4 v = *(const uint4*)(tb + ((size_t)row * TW + col) * C_ + (g << 5) + (ch << 3));
                *(uint4*)&xt[pl * PSTR + (ch << 3)] = v;
            }
        }
        __syncthreads();
        const unsigned short* wg = wb + (g << 5) + qc;
        uint4 afn[4];
        #pragma unroll
        for (int mt = 0; mt < 4; ++mt)
            afn[mt] = *(const uint4*)(wg + ((mt * 16 + n) << 6));
        #pragma unroll
        for (int tap = 0; tap < 9; ++tap) {
            uint4 afc[4];
            #pragma unroll
            for (int mt = 0; mt < 4; ++mt) afc[mt] = afn[mt];
            if (tap < 8) {
                #pragma unroll
                for (int mt = 0; mt < 4; ++mt)
                    afn[mt] = *(const uint4*)(wg + ((tap + 1) << 12) + ((mt * 16 + n) << 6));
            }
            int ki = tap / 3, kj = tap - ki * 3;
            int xl = n + kj;
            #pragma unroll
            for (int j = 0; j < 4; ++j) {
                int yl = 4 * wave + j + ki;
                bf16x8 bf = *(const bf16x8*)&xt[(yl * 18 + xl) * PSTR + qc];
                #pragma unroll
                for (int mt = 0; mt < 4; ++mt)
                    acc[mt][j] = __builtin_amdgcn_mfma_f32_16x16x32_bf16(
                        __builtin_bit_cast(bf16x8, afc[mt]), bf, acc[mt][j], 0, 0, 0);
            }
        }
    }
    // epilogue: scale by A, store NCHW fp32
    #pragma unroll
    for (int j = 0; j < 4; ++j) {
        int y = ty0 + 4 * wave + j, xx = tx0 + n;
        float a = A[(b << 14) + (y << 7) + xx];
        #pragma unroll
        for (int mt = 0; mt < 4; ++mt) {
            #pragma unroll
            for (int r = 0; r < 4; ++r) {
                int o = (mt << 4) + (q << 2) + r;
                out[(((size_t)(b * C_ + o)) << 14) + (y << 7) + xx] = acc[mt][j][r] * a;
            }
        }
    }
}

// ---------------------------------------------------------------------------
extern "C" void kernel_launch(void* const* d_in, const int* in_sizes, int n_in,
                              void* d_out, int out_size, void* d_ws, size_t ws_size,
                              hipStream_t stream) {
    const float* x      = (const float*)d_in[0];
    const float* weight = (const float*)d_in[1];
    const float* se_w1  = (const float*)d_in[2];
    const float* se_w2  = (const float*)d_in[3];
    const float* fc_w1  = (const float*)d_in[4];
    const float* fc_w2  = (const float*)d_in[5];
    float* out = (float*)d_out;

    char* ws = (char*)d_ws;
    float* y0p           = (float*)ws;             ws += (size_t)B_ * C_ * 128 * 4;   // 512 KB
    float* sgm           = (float*)ws;             ws += (size_t)B_ * K9C * 4;        // 36.9 KB
    float* A             = (float*)ws;             ws += (size_t)B_ * HW_ * 4;        // 1 MB
    unsigned short* t    = (unsigned short*)ws;    ws += (size_t)B_ * TW * TW * C_ * 2 + 4096;
    unsigned short* w_t  = (unsigned short*)ws;    ws += (size_t)B_ * 9 * C_ * C_ * 2;
    unsigned short* w1t  = (unsigned short*)ws;    ws += 9 * 16 * C_ * 2 + 2048;
    unsigned short* mid  = (unsigned short*)ws;

    k_tr  <<<B_ * H_, 256, 0, stream>>>(x, t, y0p);
    k_w1t <<<36, 256, 0, stream>>>(se_w1, w1t);
    k_fc  <<<B_, 256, 0, stream>>>(y0p, fc_w1, fc_w2, sgm);
    k_wt  <<<B_ * 9, 256, 0, stream>>>(weight, sgm, w_t);
    k_se1 <<<B_ * 64, 256, 0, stream>>>(t, w1t, mid);
    k_se2 <<<B_ * HW_ / 256, 256, 0, stream>>>(mid, se_w2, A);
    k_main<<<B_ * 64, 256, 0, stream>>>(t, w_t, A, out);
}